// Round 7
// baseline (9131.026 us; speedup 1.0000x reference)
//
#include <hip/hip_runtime.h>
#include <math.h>

#define Q 2048
#define NT 32            // 32x32 grid of 64x64 tiles
#define NOBS 8192
#define NBLK 256
#define ODPOOL (NBLK - NT)   // 224 off-diagonal owner blocks

// ---------------------------------------------------------------------------
// IF-coherent (agent-scope, L1/L2-bypassing) accessors.
__device__ __forceinline__ float2 coh_load8(const float* p) {
  unsigned long long v = __hip_atomic_load((const unsigned long long*)p,
      __ATOMIC_RELAXED, __HIP_MEMORY_SCOPE_AGENT);
  float2 r;
  r.x = __uint_as_float((unsigned)(v & 0xffffffffull));
  r.y = __uint_as_float((unsigned)(v >> 32));
  return r;
}
__device__ __forceinline__ void coh_store8(float* p, float a, float b) {
  unsigned long long v = ((unsigned long long)__float_as_uint(b) << 32) |
                         (unsigned long long)__float_as_uint(a);
  __hip_atomic_store((unsigned long long*)p, v, __ATOMIC_RELAXED,
                     __HIP_MEMORY_SCOPE_AGENT);
}
__device__ __forceinline__ float coh_load4(const float* p) {
  unsigned v = __hip_atomic_load((const unsigned*)p, __ATOMIC_RELAXED,
                                 __HIP_MEMORY_SCOPE_AGENT);
  return __uint_as_float(v);
}
__device__ __forceinline__ void coh_store4(float* p, float x) {
  __hip_atomic_store((unsigned*)p, __float_as_uint(x), __ATOMIC_RELAXED,
                     __HIP_MEMORY_SCOPE_AGENT);
}

// ---------------------------------------------------------------------------
__device__ __forceinline__ float block_sum256(float v, volatile float* red) {
  int tid = threadIdx.x;
#pragma unroll
  for (int o = 32; o > 0; o >>= 1) v += __shfl_down(v, o);
  __syncthreads();
  if ((tid & 63) == 0) red[tid >> 6] = v;
  __syncthreads();
  return red[0] + red[1] + red[2] + red[3];
}

// ---------------------------------------------------------------------------
__global__ __launch_bounds__(256) void obs_kernel(
    const float* __restrict__ yt, const float* __restrict__ yp,
    const int* __restrict__ zidx, const float* __restrict__ s2e_p,
    const float* __restrict__ s2b_p, float* __restrict__ t,
    int* __restrict__ cnt, float* __restrict__ scal) {
  __shared__ float red[4];
  int i = blockIdx.x * 256 + threadIdx.x;
  float s2e = s2e_p[0], s2b = s2b_p[0];
  float sig2 = s2e + s2b;
  float r = yt[i] - yp[i];
  float e = erff(r * rsqrtf(2.0f * sig2));
  float u = 0.5f * (e + 1.0f);
  u = fminf(fmaxf(u, 1e-5f), 1.0f - 1e-5f);
  float m = erfinvf(2.0f * u - 1.0f) * 1.4142135623730951f;
  float slp = -0.5f * logf(2.0f * 3.14159265358979f * sig2) - r * r / (2.0f * sig2);
  int z = zidx[i];
  atomicAdd(&t[z], m);
  atomicAdd(&cnt[z], 1);
  float s1 = block_sum256(slp, red);
  float s2 = block_sum256(m * m, red);
  if (threadIdx.x == 0) {
    atomicAdd(&scal[0], s1);   // sum_log_pdf
    atomicAdd(&scal[1], s2);   // m'm
  }
}

// ---------------------------------------------------------------------------
__global__ __launch_bounds__(256) void build_G(
    const float* __restrict__ dist, const float* __restrict__ s2e_p,
    const float* __restrict__ s2b_p, const float* __restrict__ ell_p,
    const int* __restrict__ cnt, float* __restrict__ G) {
  int idx = blockIdx.x * 256 + threadIdx.x;
  int j = idx >> 11;
  int k = idx & (Q - 1);
  float s2e = s2e_p[0], s2b = s2b_p[0], ell = ell_p[0];
  float sig2 = s2e + s2b;
  float a = (s2b / sig2) * expf(-dist[idx] / (2.0f * ell));
  float g = sqrtf((float)cnt[j] * (float)cnt[k]) * a;
  if (j == k) g += s2e / sig2;
  G[idx] = g;
}

// ---------------------------------------------------------------------------
__global__ __launch_bounds__(256) void matvec_kernel(
    const float* __restrict__ dist, const float* __restrict__ s2e_p,
    const float* __restrict__ s2b_p, const float* __restrict__ ell_p,
    const int* __restrict__ cnt, const float* __restrict__ t,
    float* __restrict__ z, float* __restrict__ scal) {
  __shared__ float red[4];
  int j = blockIdx.x;
  float s2e = s2e_p[0], s2b = s2b_p[0], ell = ell_p[0];
  float sig2 = s2e + s2b;
  float inv2ell = 1.0f / (2.0f * ell);
  float s = 0.0f;
  const float* drow = dist + (size_t)j * Q;
  for (int k = threadIdx.x; k < Q; k += 256) s += expf(-drow[k] * inv2ell) * t[k];
  float tot = block_sum256(s, red);
  if (threadIdx.x == 0) {
    float wj = (s2b / sig2) * tot;
    z[j] = sqrtf((float)cnt[j]) * wj;   // b = W^{1/2} w
    atomicAdd(&scal[2], t[j] * wj);     // t.w
  }
}

// ---------------------------------------------------------------------------
// Dataflow left-looking Cholesky: zero grid barriers. Tile (i,j) owned by one
// block; k-sum accumulated in registers; per-tile ready flags via IF atomics.
// Pre-finalization accesses are ONLY coherent (never populate L1/L2);
// post-flag panel reads use cached float4 loads (data is immutable then).
__global__ __launch_bounds__(256) void chol_df(
    float* __restrict__ G, float* __restrict__ z, float* __restrict__ scal,
    int* __restrict__ rdy, const float* __restrict__ s2e_p,
    const float* __restrict__ s2b_p, float* __restrict__ out) {
  __shared__ __align__(16) float shA[64 * 68];   // 17.4 KB
  __shared__ __align__(16) float shB[64 * 68];   // 17.4 KB (also diag @65)
  int tid = threadIdx.x, lane = tid & 63, wv = tid >> 6;
  int tx = tid & 15, ty = tid >> 4;
  int bx = blockIdx.x;

  // ---- static ownership: blocks 0..31 own diag j=bx; 32..255 off-diag ----
  // Unowned slots sentinel: oj = -1 (inert in both oj==k and oj>k tests).
  int dj = (bx < NT) ? bx : -1;
  int oi0 = -1, oj0 = -1, oi1 = -1, oj1 = -1, oi2 = -1, oj2 = -1;
  if (dj < 0) {
    int nod = 0, idx = 0;
    for (int j = 0; j < NT; ++j)
      for (int i = j + 1; i < NT; ++i) {
        if ((idx % ODPOOL) + NT == bx) {
          if (nod == 0)      { oi0 = i; oj0 = j; }
          else if (nod == 1) { oi1 = i; oj1 = j; }
          else               { oi2 = i; oj2 = j; }
          ++nod;
        }
        ++idx;
      }
  }

  // ---- helpers ----
  auto waitflag = [&](const int* f) {
    if (tid == 0) {
      while (__hip_atomic_load(f, __ATOMIC_RELAXED,
                               __HIP_MEMORY_SCOPE_AGENT) == 0) { }
    }
    __syncthreads();
  };
  auto setflag = [&](int* f) {   // caller: vmcnt drained, one thread
    __hip_atomic_store(f, 1, __ATOMIC_RELAXED, __HIP_MEMORY_SCOPE_AGENT);
  };
  // cached transposed staging of a FINALIZED tile: sh[c*68+r] = T[r][c]
  auto stage_T = [&](const float* Gt, float* sh) {
    for (int it = 0; it < 4; ++it) {
      int idx = it * 256 + tid, r = idx >> 4, c4 = (idx & 15) * 4;
      float4 v = *(const float4*)(Gt + (size_t)r * Q + c4);
      sh[(c4 + 0) * 68 + r] = v.x; sh[(c4 + 1) * 68 + r] = v.y;
      sh[(c4 + 2) * 68 + r] = v.z; sh[(c4 + 3) * 68 + r] = v.w;
    }
  };
  auto mac16 = [&](const float* sA, const float* sB, float (&acc)[16]) {
    for (int p = 0; p < 64; ++p) {
      float4 a4 = *(const float4*)&sA[p * 68 + ty * 4];
      float4 b4 = *(const float4*)&sB[p * 68 + tx * 4];
      float av[4] = {a4.x, a4.y, a4.z, a4.w};
      float bv[4] = {b4.x, b4.y, b4.z, b4.w};
#pragma unroll
      for (int i4 = 0; i4 < 4; ++i4)
#pragma unroll
        for (int jj = 0; jj < 4; ++jj) acc[i4 * 4 + jj] -= av[i4] * bv[jj];
    }
  };
  auto init_acc = [&](float (&acc)[16], int ii, int jj) {  // COHERENT base read
    const float* B = G + (size_t)(ii * 64) * Q + jj * 64;
#pragma unroll
    for (int i4 = 0; i4 < 4; ++i4) {
      const float* rp = B + (size_t)(ty * 4 + i4) * Q + tx * 4;
      float2 u0 = coh_load8(rp), u1 = coh_load8(rp + 2);
      acc[i4 * 4 + 0] = u0.x; acc[i4 * 4 + 1] = u0.y;
      acc[i4 * 4 + 2] = u1.x; acc[i4 * 4 + 3] = u1.y;
    }
  };
  auto do_term = [&](float (&acc)[16], int ii, int jj, int k) {
    waitflag(&rdy[ii * NT + k]);
    waitflag(&rdy[jj * NT + k]);
    stage_T(G + (size_t)(ii * 64) * Q + k * 64, shA);
    stage_T(G + (size_t)(jj * 64) * Q + k * 64, shB);
    __syncthreads();
    mac16(shA, shB, acc);
    __syncthreads();
  };
  auto do_trsm = [&](float (&acc)[16], int ii, int jj) {
    waitflag(&rdy[jj * NT + jj]);
    // acc tile -> shA (stride 68, row-major)
#pragma unroll
    for (int i4 = 0; i4 < 4; ++i4)
#pragma unroll
      for (int c4 = 0; c4 < 4; ++c4)
        shA[(ty * 4 + i4) * 68 + tx * 4 + c4] = acc[i4 * 4 + c4];
    // factored diag (finalized, immutable) -> shB cached, stride 65
    const float* D = G + (size_t)(jj * 64) * Q + jj * 64;
    for (int it = 0; it < 4; ++it) {
      int idx = it * 256 + tid, r = idx >> 4, c4 = (idx & 15) * 4;
      float4 v = *(const float4*)(D + (size_t)r * Q + c4);
      shB[r * 65 + c4 + 0] = v.x; shB[r * 65 + c4 + 1] = v.y;
      shB[r * 65 + c4 + 2] = v.z; shB[r * 65 + c4 + 3] = v.w;
    }
    __syncthreads();
    float dinv = 1.0f / shB[lane * 65 + lane];
    float* dst = G + (size_t)(ii * 64) * Q + jj * 64;
    for (int r16 = 0; r16 < 16; ++r16) {
      int r = wv * 16 + r16;
      float a = shA[r * 68 + lane];
      for (int p = 0; p < 64; ++p) {
        float xp = __shfl(a, p) * __shfl(dinv, p);
        if (lane > p) a -= xp * shB[lane * 65 + p];
      }
      coh_store4(dst + (size_t)r * Q + lane, a * dinv);
    }
    asm volatile("s_waitcnt vmcnt(0)" ::: "memory");
    __syncthreads();
    if (tid == 0) setflag(&rdy[ii * NT + jj]);
    __syncthreads();
  };

  // ---- init accumulators (coherent: no cache line ever holds pre-final data)
  float accD[16], accO0[16], accO1[16], accO2[16];
  if (dj >= 0) init_acc(accD, dj, dj);
  if (oj0 >= 0) init_acc(accO0, oi0, oj0);
  if (oj1 >= 0) init_acc(accO1, oi1, oj1);
  if (oj2 >= 0) init_acc(accO2, oi2, oj2);
  float zacc = 0.0f;
  if (dj >= 0 && wv == 0) zacc = coh_load4(z + dj * 64 + lane);

  // ---- dataflow main loop over k ----
  for (int k = 0; k < NT; ++k) {
    // (a) finalize own diag tile
    if (dj == k) {
      __syncthreads();
#pragma unroll
      for (int i4 = 0; i4 < 4; ++i4)
#pragma unroll
        for (int c4 = 0; c4 < 4; ++c4)
          shA[(ty * 4 + i4) * 68 + tx * 4 + c4] = accD[i4 * 4 + c4];
      __syncthreads();
      if (wv == 0) {
        float rr[64];
#pragma unroll
        for (int k4 = 0; k4 < 16; ++k4) {
          float4 v = *(const float4*)&shA[lane * 68 + k4 * 4];
          rr[k4 * 4 + 0] = v.x; rr[k4 * 4 + 1] = v.y;
          rr[k4 * 4 + 2] = v.z; rr[k4 * 4 + 3] = v.w;
        }
#pragma unroll
        for (int jj = 0; jj < 64; ++jj) {
          float vjj = __shfl(rr[jj], jj);
          float invd = rsqrtf(vjj);
          float lij = rr[jj] * invd;   // lane jj gets sqrt(vjj)
          rr[jj] = lij;
#pragma unroll
          for (int kk = 0; kk < 64; ++kk)
            if (kk > jj) rr[kk] -= lij * __shfl(lij, kk);
        }
        float dv = 1.0f;
#pragma unroll
        for (int kk = 0; kk < 64; ++kk)
          if (kk == lane) dv = rr[kk];
        float lg = logf(dv);
#pragma unroll
        for (int o = 32; o > 0; o >>= 1) lg += __shfl_down(lg, o);
        if (lane == 0) atomicAdd(&scal[3], lg);
        // store factored diag (upper zeroed), coherent
        float* dst = G + (size_t)(k * 64) * Q + k * 64;
#pragma unroll
        for (int k2 = 0; k2 < 32; ++k2) {
          float a0 = (k2 * 2     <= lane) ? rr[k2 * 2]     : 0.0f;
          float a1 = (k2 * 2 + 1 <= lane) ? rr[k2 * 2 + 1] : 0.0f;
          coh_store8(dst + (size_t)lane * Q + k2 * 2, a0, a1);
        }
        // z forward-solve for this 64-chunk
        float dzi = 1.0f / dv;
        float a = zacc;
        for (int p = 0; p < 64; ++p) {
          float xp = __shfl(a, p) * __shfl(dzi, p);
          if (lane > p) a -= xp * rr[p];
        }
        a *= dzi;
        coh_store4(z + k * 64 + lane, a);
        asm volatile("s_waitcnt vmcnt(0)" ::: "memory");
        if (lane == 0) setflag(&rdy[k * NT + k]);
        // last diag: assemble the final loss (all deps transitively done)
        if (k == NT - 1) {
          float bv = 0.0f;
          for (int p = 0; p < NT; ++p) {
            float zi = coh_load4(z + p * 64 + lane);
            bv += zi * zi;
          }
#pragma unroll
          for (int o = 32; o > 0; o >>= 1) bv += __shfl_down(bv, o);
          if (lane == 0) {
            float s2e = s2e_p[0], s2b = s2b_p[0];
            float sig2 = s2e + s2b;
            float c = s2e / sig2;
            float slp = coh_load4(&scal[0]), mtm = coh_load4(&scal[1]);
            float tw = coh_load4(&scal[2]), sl = coh_load4(&scal[3]);
            float tty = (tw - bv) / c;
            float mrm = (mtm - tty) / c;
            float logdetR = (float)(NOBS - Q) * logf(c) + 2.0f * sl;
            coh_store4(out,
                0.5f * logdetR + 0.5f * mrm - 0.5f * mtm + 0.5f * slp);
          }
        }
      }
      __syncthreads();
    }

    // (b) finalize own off-diag tiles in column k (TRSM)
    if (oj0 == k) do_trsm(accO0, oi0, k);
    if (oj1 == k) do_trsm(accO1, oi1, k);
    if (oj2 == k) do_trsm(accO2, oi2, k);

    // (c) rank-64 updates with panel column k
    if (dj > k) {
      waitflag(&rdy[dj * NT + k]);
      stage_T(G + (size_t)(dj * 64) * Q + k * 64, shA);
      __syncthreads();
      mac16(shA, shA, accD);
      if (wv == 0) {   // z-chunk update: z_dj -= L(dj,k) z_k
        float zk = coh_load4(z + k * 64 + lane);
        for (int p = 0; p < 64; ++p) {
          float zv = __shfl(zk, p);
          zacc -= shA[p * 68 + lane] * zv;   // shA[p*68+c] = L[c][p]
        }
      }
      __syncthreads();
    }
    if (oj0 > k) do_term(accO0, oi0, oj0, k);
    if (oj1 > k) do_term(accO1, oi1, oj1, k);
    if (oj2 > k) do_term(accO2, oi2, oj2, k);
  }
}

// ---------------------------------------------------------------------------
extern "C" void kernel_launch(void* const* d_in, const int* in_sizes, int n_in,
                              void* d_out, int out_size, void* d_ws, size_t ws_size,
                              hipStream_t stream) {
  const float* yt   = (const float*)d_in[0];
  const float* yp   = (const float*)d_in[1];
  const int*   zidx = (const int*)d_in[2];
  const float* dist = (const float*)d_in[3];
  const float* s2e  = (const float*)d_in[4];
  const float* s2b  = (const float*)d_in[5];
  const float* ell  = (const float*)d_in[6];

  float* ws   = (float*)d_ws;
  float* G    = ws;                         // Q*Q floats = 16 MB
  float* z    = ws + (size_t)Q * Q;         // Q
  float* t    = z + Q;                      // Q
  int*   cnt  = (int*)(t + Q);              // Q ints
  float* scal = t + 2 * Q;                  // 8: slp, mtm, tw, sumlogL
  int*   rdy  = (int*)(scal + 8);           // NT*NT tile-ready flags

  // zero t, cnt, scal, rdy (flags MUST be re-zeroed every launch)
  hipMemsetAsync(t, 0, (2 * Q + 8 + NT * NT) * sizeof(float), stream);

  obs_kernel<<<NOBS / 256, 256, 0, stream>>>(yt, yp, zidx, s2e, s2b, t, cnt, scal);
  build_G<<<(Q * Q) / 256, 256, 0, stream>>>(dist, s2e, s2b, ell, cnt, G);
  matvec_kernel<<<Q, 256, 0, stream>>>(dist, s2e, s2b, ell, cnt, t, z, scal);

  chol_df<<<dim3(NBLK), dim3(256), 0, stream>>>(
      G, z, scal, rdy, s2e, s2b, (float*)d_out);
}

// Round 8
// 7752.921 us; speedup vs baseline: 1.1778x; 1.1778x over previous
//
#include <hip/hip_runtime.h>
#include <math.h>

#define Q 2048
#define NT 32            // 32x32 grid of 64x64 tiles
#define NOBS 8192
#define NBLK 256
#define ODPOOL (NBLK - NT)   // 224 off-diagonal owner blocks
#define FPAD 16              // flag padding: 16 ints = 64B per flag

// ---------------------------------------------------------------------------
// IF-coherent (agent-scope, L1/L2-bypassing) accessors.
__device__ __forceinline__ float2 coh_load8(const float* p) {
  unsigned long long v = __hip_atomic_load((const unsigned long long*)p,
      __ATOMIC_RELAXED, __HIP_MEMORY_SCOPE_AGENT);
  float2 r;
  r.x = __uint_as_float((unsigned)(v & 0xffffffffull));
  r.y = __uint_as_float((unsigned)(v >> 32));
  return r;
}
__device__ __forceinline__ void coh_store8(float* p, float a, float b) {
  unsigned long long v = ((unsigned long long)__float_as_uint(b) << 32) |
                         (unsigned long long)__float_as_uint(a);
  __hip_atomic_store((unsigned long long*)p, v, __ATOMIC_RELAXED,
                     __HIP_MEMORY_SCOPE_AGENT);
}
__device__ __forceinline__ float coh_load4(const float* p) {
  unsigned v = __hip_atomic_load((const unsigned*)p, __ATOMIC_RELAXED,
                                 __HIP_MEMORY_SCOPE_AGENT);
  return __uint_as_float(v);
}
__device__ __forceinline__ void coh_store4(float* p, float x) {
  __hip_atomic_store((unsigned*)p, __float_as_uint(x), __ATOMIC_RELAXED,
                     __HIP_MEMORY_SCOPE_AGENT);
}

// ---------------------------------------------------------------------------
__device__ __forceinline__ float block_sum256(float v, volatile float* red) {
  int tid = threadIdx.x;
#pragma unroll
  for (int o = 32; o > 0; o >>= 1) v += __shfl_down(v, o);
  __syncthreads();
  if ((tid & 63) == 0) red[tid >> 6] = v;
  __syncthreads();
  return red[0] + red[1] + red[2] + red[3];
}

// ---------------------------------------------------------------------------
__global__ __launch_bounds__(256) void obs_kernel(
    const float* __restrict__ yt, const float* __restrict__ yp,
    const int* __restrict__ zidx, const float* __restrict__ s2e_p,
    const float* __restrict__ s2b_p, float* __restrict__ t,
    int* __restrict__ cnt, float* __restrict__ scal) {
  __shared__ float red[4];
  int i = blockIdx.x * 256 + threadIdx.x;
  float s2e = s2e_p[0], s2b = s2b_p[0];
  float sig2 = s2e + s2b;
  float r = yt[i] - yp[i];
  float e = erff(r * rsqrtf(2.0f * sig2));
  float u = 0.5f * (e + 1.0f);
  u = fminf(fmaxf(u, 1e-5f), 1.0f - 1e-5f);
  float m = erfinvf(2.0f * u - 1.0f) * 1.4142135623730951f;
  float slp = -0.5f * logf(2.0f * 3.14159265358979f * sig2) - r * r / (2.0f * sig2);
  int z = zidx[i];
  atomicAdd(&t[z], m);
  atomicAdd(&cnt[z], 1);
  float s1 = block_sum256(slp, red);
  float s2 = block_sum256(m * m, red);
  if (threadIdx.x == 0) {
    atomicAdd(&scal[0], s1);   // sum_log_pdf
    atomicAdd(&scal[1], s2);   // m'm
  }
}

// ---------------------------------------------------------------------------
__global__ __launch_bounds__(256) void build_G(
    const float* __restrict__ dist, const float* __restrict__ s2e_p,
    const float* __restrict__ s2b_p, const float* __restrict__ ell_p,
    const int* __restrict__ cnt, float* __restrict__ G) {
  int idx = blockIdx.x * 256 + threadIdx.x;
  int j = idx >> 11;
  int k = idx & (Q - 1);
  float s2e = s2e_p[0], s2b = s2b_p[0], ell = ell_p[0];
  float sig2 = s2e + s2b;
  float a = (s2b / sig2) * expf(-dist[idx] / (2.0f * ell));
  float g = sqrtf((float)cnt[j] * (float)cnt[k]) * a;
  if (j == k) g += s2e / sig2;
  G[idx] = g;
}

// ---------------------------------------------------------------------------
__global__ __launch_bounds__(256) void matvec_kernel(
    const float* __restrict__ dist, const float* __restrict__ s2e_p,
    const float* __restrict__ s2b_p, const float* __restrict__ ell_p,
    const int* __restrict__ cnt, const float* __restrict__ t,
    float* __restrict__ z, float* __restrict__ scal) {
  __shared__ float red[4];
  int j = blockIdx.x;
  float s2e = s2e_p[0], s2b = s2b_p[0], ell = ell_p[0];
  float sig2 = s2e + s2b;
  float inv2ell = 1.0f / (2.0f * ell);
  float s = 0.0f;
  const float* drow = dist + (size_t)j * Q;
  for (int k = threadIdx.x; k < Q; k += 256) s += expf(-drow[k] * inv2ell) * t[k];
  float tot = block_sum256(s, red);
  if (threadIdx.x == 0) {
    float wj = (s2b / sig2) * tot;
    z[j] = sqrtf((float)cnt[j]) * wj;   // b = W^{1/2} w
    atomicAdd(&scal[2], t[j] * wj);     // t.w
  }
}

// ---------------------------------------------------------------------------
// Dataflow left-looking Cholesky, zero grid barriers.
//  - diag block j owns diag tile (j,j) AND subdiagonal tile (j,j-1) + z chunk
//    -> ONE cross-block hop per column on the critical path.
//  - 224 off-diag blocks own tiles with i >= j+2 (465 tiles, <=3 each).
//  - flags padded to 64B; polls use s_sleep backoff.
//  - pre-finalization data moves ONLY via IF-coherent ops (no stale caches);
//    post-flag reads of immutable tiles use cached float4 loads.
__global__ __launch_bounds__(256) void chol_df(
    float* __restrict__ G, float* __restrict__ z, float* __restrict__ scal,
    int* __restrict__ rdy, const float* __restrict__ s2e_p,
    const float* __restrict__ s2b_p, float* __restrict__ out) {
  __shared__ __align__(16) float shA[64 * 68];   // 17.4 KB
  __shared__ __align__(16) float shB[64 * 68];   // 17.4 KB (diag tile @65)
  __shared__ __align__(16) float shT[64 * 68];   // 17.4 KB (TRSM result, T)
  int tid = threadIdx.x, lane = tid & 63, wv = tid >> 6;
  int tx = tid & 15, ty = tid >> 4;
  int bx = blockIdx.x;

  int dj = (bx < NT) ? bx : -1;
  int oi0 = -1, oj0 = -1, oi1 = -1, oj1 = -1, oi2 = -1, oj2 = -1;
  if (dj < 0) {
    int nod = 0, idx = 0;
    for (int j = 0; j < NT; ++j)
      for (int i = j + 2; i < NT; ++i) {   // pool: strictly below subdiagonal
        if ((idx % ODPOOL) + NT == bx) {
          if (nod == 0)      { oi0 = i; oj0 = j; }
          else if (nod == 1) { oi1 = i; oj1 = j; }
          else               { oi2 = i; oj2 = j; }
          ++nod;
        }
        ++idx;
      }
  }

  auto FLAG = [&](int i, int k) { return rdy + (i * NT + k) * FPAD; };
  auto waitflag = [&](const int* f) {
    if (tid == 0) {
      while (__hip_atomic_load(f, __ATOMIC_RELAXED,
                               __HIP_MEMORY_SCOPE_AGENT) == 0)
        __builtin_amdgcn_s_sleep(4);
    }
    __syncthreads();
  };
  auto waitflag2 = [&](const int* f1, const int* f2) {
    if (tid == 0) {
      while (__hip_atomic_load(f1, __ATOMIC_RELAXED,
                               __HIP_MEMORY_SCOPE_AGENT) == 0)
        __builtin_amdgcn_s_sleep(4);
      while (__hip_atomic_load(f2, __ATOMIC_RELAXED,
                               __HIP_MEMORY_SCOPE_AGENT) == 0)
        __builtin_amdgcn_s_sleep(4);
    }
    __syncthreads();
  };
  auto setflag = [&](int* f) {
    __hip_atomic_store(f, 1, __ATOMIC_RELAXED, __HIP_MEMORY_SCOPE_AGENT);
  };
  // cached transposed staging of a FINALIZED tile: sh[c*68+r] = T[r][c]
  auto stage_T = [&](const float* Gt, float* sh) {
    for (int it = 0; it < 4; ++it) {
      int idx = it * 256 + tid, r = idx >> 4, c4 = (idx & 15) * 4;
      float4 v = *(const float4*)(Gt + (size_t)r * Q + c4);
      sh[(c4 + 0) * 68 + r] = v.x; sh[(c4 + 1) * 68 + r] = v.y;
      sh[(c4 + 2) * 68 + r] = v.z; sh[(c4 + 3) * 68 + r] = v.w;
    }
  };
  auto mac16 = [&](const float* sA, const float* sB, float (&acc)[16]) {
    for (int p = 0; p < 64; ++p) {
      float4 a4 = *(const float4*)&sA[p * 68 + ty * 4];
      float4 b4 = *(const float4*)&sB[p * 68 + tx * 4];
      float av[4] = {a4.x, a4.y, a4.z, a4.w};
      float bv[4] = {b4.x, b4.y, b4.z, b4.w};
#pragma unroll
      for (int i4 = 0; i4 < 4; ++i4)
#pragma unroll
        for (int jj = 0; jj < 4; ++jj) acc[i4 * 4 + jj] -= av[i4] * bv[jj];
    }
  };
  auto init_acc = [&](float (&acc)[16], int ii, int jj) {  // COHERENT base read
    const float* B = G + (size_t)(ii * 64) * Q + jj * 64;
#pragma unroll
    for (int i4 = 0; i4 < 4; ++i4) {
      const float* rp = B + (size_t)(ty * 4 + i4) * Q + tx * 4;
      float2 u0 = coh_load8(rp), u1 = coh_load8(rp + 2);
      acc[i4 * 4 + 0] = u0.x; acc[i4 * 4 + 1] = u0.y;
      acc[i4 * 4 + 2] = u1.x; acc[i4 * 4 + 3] = u1.y;
    }
  };
  auto do_term = [&](float (&acc)[16], int ii, int jj, int k) {
    waitflag2(FLAG(ii, k), FLAG(jj, k));
    stage_T(G + (size_t)(ii * 64) * Q + k * 64, shA);
    stage_T(G + (size_t)(jj * 64) * Q + k * 64, shB);
    __syncthreads();
    mac16(shA, shB, acc);
    __syncthreads();
  };
  // TRSM tile (ii,jj) from acc; optionally keep transposed result in shT.
  auto do_trsm = [&](float (&acc)[16], int ii, int jj, bool keepT) {
    waitflag(FLAG(jj, jj));
#pragma unroll
    for (int i4 = 0; i4 < 4; ++i4)
#pragma unroll
      for (int c4 = 0; c4 < 4; ++c4)
        shA[(ty * 4 + i4) * 68 + tx * 4 + c4] = acc[i4 * 4 + c4];
    const float* D = G + (size_t)(jj * 64) * Q + jj * 64;   // finalized diag
    for (int it = 0; it < 4; ++it) {
      int idx = it * 256 + tid, r = idx >> 4, c4 = (idx & 15) * 4;
      float4 v = *(const float4*)(D + (size_t)r * Q + c4);
      shB[r * 65 + c4 + 0] = v.x; shB[r * 65 + c4 + 1] = v.y;
      shB[r * 65 + c4 + 2] = v.z; shB[r * 65 + c4 + 3] = v.w;
    }
    __syncthreads();
    float dinv = 1.0f / shB[lane * 65 + lane];
    float* dst = G + (size_t)(ii * 64) * Q + jj * 64;
    for (int r16 = 0; r16 < 16; ++r16) {
      int r = wv * 16 + r16;
      float a = shA[r * 68 + lane];
      for (int p = 0; p < 64; ++p) {
        float xp = __shfl(a, p) * __shfl(dinv, p);
        if (lane > p) a -= xp * shB[lane * 65 + p];
      }
      float xr = a * dinv;
      coh_store4(dst + (size_t)r * Q + lane, xr);
      if (keepT) shT[lane * 68 + r] = xr;
    }
    asm volatile("s_waitcnt vmcnt(0)" ::: "memory");
    __syncthreads();
    if (tid == 0) setflag(FLAG(ii, jj));
    __syncthreads();
  };

  if (dj >= 0) {
    // =================== diag block: (dj,dj), (dj,dj-1), z chunk ==========
    float accD[16], accS[16];
    init_acc(accD, dj, dj);
    if (dj >= 1) init_acc(accS, dj, dj - 1);
    float zacc = 0.0f;
    if (wv == 0) zacc = coh_load4(z + dj * 64 + lane);

    for (int k = 0; k < dj - 1; ++k) {
      waitflag2(FLAG(dj, k), FLAG(dj - 1, k));
      stage_T(G + (size_t)(dj * 64) * Q + k * 64, shA);
      stage_T(G + (size_t)(dj - 1) * 64 * Q + k * 64, shB);
      __syncthreads();
      mac16(shA, shA, accD);
      mac16(shA, shB, accS);
      if (wv == 0) {   // z_dj -= L(dj,k) z_k   (z_k final: column-k flags imply diag k)
        float zk = coh_load4(z + k * 64 + lane);
        for (int p = 0; p < 64; ++p)
          zacc -= shA[p * 68 + lane] * __shfl(zk, p);
      }
      __syncthreads();
    }
    if (dj >= 1) {
      do_trsm(accS, dj, dj - 1, true);         // critical hop: waits diag(dj-1)
      mac16(shT, shT, accD);
      if (wv == 0) {
        float zk = coh_load4(z + (dj - 1) * 64 + lane);
        for (int p = 0; p < 64; ++p)
          zacc -= shT[p * 68 + lane] * __shfl(zk, p);
      }
      __syncthreads();
    }
    // factor accD
#pragma unroll
    for (int i4 = 0; i4 < 4; ++i4)
#pragma unroll
      for (int c4 = 0; c4 < 4; ++c4)
        shA[(ty * 4 + i4) * 68 + tx * 4 + c4] = accD[i4 * 4 + c4];
    __syncthreads();
    if (wv == 0) {
      float rr[64];
#pragma unroll
      for (int k4 = 0; k4 < 16; ++k4) {
        float4 v = *(const float4*)&shA[lane * 68 + k4 * 4];
        rr[k4 * 4 + 0] = v.x; rr[k4 * 4 + 1] = v.y;
        rr[k4 * 4 + 2] = v.z; rr[k4 * 4 + 3] = v.w;
      }
#pragma unroll
      for (int jj = 0; jj < 64; ++jj) {
        float vjj = __shfl(rr[jj], jj);
        float invd = rsqrtf(vjj);
        float lij = rr[jj] * invd;   // lane jj gets sqrt(vjj)
        rr[jj] = lij;
#pragma unroll
        for (int kk = 0; kk < 64; ++kk)
          if (kk > jj) rr[kk] -= lij * __shfl(lij, kk);
      }
      float dv = 1.0f;
#pragma unroll
      for (int kk = 0; kk < 64; ++kk)
        if (kk == lane) dv = rr[kk];
      float lg = logf(dv);
#pragma unroll
      for (int o = 32; o > 0; o >>= 1) lg += __shfl_down(lg, o);
      if (lane == 0) atomicAdd(&scal[3], lg);
      float* dst = G + (size_t)(dj * 64) * Q + dj * 64;
#pragma unroll
      for (int k2 = 0; k2 < 32; ++k2) {
        float a0 = (k2 * 2     <= lane) ? rr[k2 * 2]     : 0.0f;
        float a1 = (k2 * 2 + 1 <= lane) ? rr[k2 * 2 + 1] : 0.0f;
        coh_store8(dst + (size_t)lane * Q + k2 * 2, a0, a1);
      }
      // z forward-solve this chunk
      float dzi = 1.0f / dv;
      float a = zacc;
      for (int p = 0; p < 64; ++p) {
        float xp = __shfl(a, p) * __shfl(dzi, p);
        if (lane > p) a -= xp * rr[p];
      }
      a *= dzi;
      coh_store4(z + dj * 64 + lane, a);
      asm volatile("s_waitcnt vmcnt(0)" ::: "memory");
      if (lane == 0) setflag(FLAG(dj, dj));
      if (dj == NT - 1) {   // all deps transitively final
        float bv = 0.0f;
        for (int p = 0; p < NT; ++p) {
          float zi = coh_load4(z + p * 64 + lane);
          bv += zi * zi;
        }
#pragma unroll
        for (int o = 32; o > 0; o >>= 1) bv += __shfl_down(bv, o);
        if (lane == 0) {
          float s2e = s2e_p[0], s2b = s2b_p[0];
          float sig2 = s2e + s2b;
          float c = s2e / sig2;
          float slp = coh_load4(&scal[0]), mtm = coh_load4(&scal[1]);
          float tw = coh_load4(&scal[2]), sl = coh_load4(&scal[3]);
          float tty = (tw - bv) / c;
          float mrm = (mtm - tty) / c;
          float logdetR = (float)(NOBS - Q) * logf(c) + 2.0f * sl;
          coh_store4(out,
              0.5f * logdetR + 0.5f * mrm - 0.5f * mtm + 0.5f * slp);
        }
      }
    }
  } else {
    // =================== off-diag pool block: up to 3 tiles, i>=j+2 =======
    float accO0[16], accO1[16], accO2[16];
    if (oj0 >= 0) init_acc(accO0, oi0, oj0);
    if (oj1 >= 0) init_acc(accO1, oi1, oj1);
    if (oj2 >= 0) init_acc(accO2, oi2, oj2);
    for (int k = 0; k < NT; ++k) {
      if (oj0 == k) do_trsm(accO0, oi0, k, false);
      if (oj1 == k) do_trsm(accO1, oi1, k, false);
      if (oj2 == k) do_trsm(accO2, oi2, k, false);
      if (oj0 > k) do_term(accO0, oi0, oj0, k);
      if (oj1 > k) do_term(accO1, oi1, oj1, k);
      if (oj2 > k) do_term(accO2, oi2, oj2, k);
    }
  }
}

// ---------------------------------------------------------------------------
extern "C" void kernel_launch(void* const* d_in, const int* in_sizes, int n_in,
                              void* d_out, int out_size, void* d_ws, size_t ws_size,
                              hipStream_t stream) {
  const float* yt   = (const float*)d_in[0];
  const float* yp   = (const float*)d_in[1];
  const int*   zidx = (const int*)d_in[2];
  const float* dist = (const float*)d_in[3];
  const float* s2e  = (const float*)d_in[4];
  const float* s2b  = (const float*)d_in[5];
  const float* ell  = (const float*)d_in[6];

  float* ws   = (float*)d_ws;
  float* G    = ws;                         // Q*Q floats = 16 MB
  float* z    = ws + (size_t)Q * Q;         // Q
  float* t    = z + Q;                      // Q
  int*   cnt  = (int*)(t + Q);              // Q ints
  float* scal = t + 2 * Q;                  // 8: slp, mtm, tw, sumlogL
  int*   rdy  = (int*)(scal + 8);           // NT*NT flags, 64B-padded

  // zero t, cnt, scal, rdy (flags MUST be re-zeroed every launch)
  hipMemsetAsync(t, 0, (2 * Q + 8 + NT * NT * FPAD) * sizeof(float), stream);

  obs_kernel<<<NOBS / 256, 256, 0, stream>>>(yt, yp, zidx, s2e, s2b, t, cnt, scal);
  build_G<<<(Q * Q) / 256, 256, 0, stream>>>(dist, s2e, s2b, ell, cnt, G);
  matvec_kernel<<<Q, 256, 0, stream>>>(dist, s2e, s2b, ell, cnt, t, z, scal);

  chol_df<<<dim3(NBLK), dim3(256), 0, stream>>>(
      G, z, scal, rdy, s2e, s2b, (float*)d_out);
}

// Round 10
// 7563.922 us; speedup vs baseline: 1.2072x; 1.0250x over previous
//
#include <hip/hip_runtime.h>
#include <math.h>

#define Q 2048
#define NT 32            // 32x32 grid of 64x64 tiles
#define NOBS 8192
#define NBLK 256
#define ODPOOL (NBLK - NT)   // 224 off-diagonal owner blocks
#define FPAD 16              // flag padding: 16 ints = 64B per flag

// ---------------------------------------------------------------------------
// IF-coherent (agent-scope) accessors.
__device__ __forceinline__ float2 coh_load8(const float* p) {
  unsigned long long v = __hip_atomic_load((const unsigned long long*)p,
      __ATOMIC_RELAXED, __HIP_MEMORY_SCOPE_AGENT);
  float2 r;
  r.x = __uint_as_float((unsigned)(v & 0xffffffffull));
  r.y = __uint_as_float((unsigned)(v >> 32));
  return r;
}
__device__ __forceinline__ void coh_store8(float* p, float a, float b) {
  unsigned long long v = ((unsigned long long)__float_as_uint(b) << 32) |
                         (unsigned long long)__float_as_uint(a);
  __hip_atomic_store((unsigned long long*)p, v, __ATOMIC_RELAXED,
                     __HIP_MEMORY_SCOPE_AGENT);
}
__device__ __forceinline__ float coh_load4(const float* p) {
  unsigned v = __hip_atomic_load((const unsigned*)p, __ATOMIC_RELAXED,
                                 __HIP_MEMORY_SCOPE_AGENT);
  return __uint_as_float(v);
}
__device__ __forceinline__ void coh_store4(float* p, float x) {
  __hip_atomic_store((unsigned*)p, __float_as_uint(x), __ATOMIC_RELAXED,
                     __HIP_MEMORY_SCOPE_AGENT);
}

// Dependent-FMA burn: keeps the SIMD issuing without flooding memory.
__device__ __forceinline__ void fma_burn(int n) {
  float x = 0.0f;
  float a = 1.0e-8f, b = 1.0e-8f;
  for (int i = 0; i < n; ++i)
    asm volatile("v_fmac_f32 %0, %1, %2" : "+v"(x) : "v"(a), "v"(b));
  asm volatile("" :: "v"(x));   // sink
}

// ---------------------------------------------------------------------------
__device__ __forceinline__ float block_sum256(float v, volatile float* red) {
  int tid = threadIdx.x;
#pragma unroll
  for (int o = 32; o > 0; o >>= 1) v += __shfl_down(v, o);
  __syncthreads();
  if ((tid & 63) == 0) red[tid >> 6] = v;
  __syncthreads();
  return red[0] + red[1] + red[2] + red[3];
}

// ---------------------------------------------------------------------------
__global__ __launch_bounds__(256) void obs_kernel(
    const float* __restrict__ yt, const float* __restrict__ yp,
    const int* __restrict__ zidx, const float* __restrict__ s2e_p,
    const float* __restrict__ s2b_p, float* __restrict__ t,
    int* __restrict__ cnt, float* __restrict__ scal) {
  __shared__ float red[4];
  int i = blockIdx.x * 256 + threadIdx.x;
  float s2e = s2e_p[0], s2b = s2b_p[0];
  float sig2 = s2e + s2b;
  float r = yt[i] - yp[i];
  float e = erff(r * rsqrtf(2.0f * sig2));
  float u = 0.5f * (e + 1.0f);
  u = fminf(fmaxf(u, 1e-5f), 1.0f - 1e-5f);
  float m = erfinvf(2.0f * u - 1.0f) * 1.4142135623730951f;
  float slp = -0.5f * logf(2.0f * 3.14159265358979f * sig2) - r * r / (2.0f * sig2);
  int z = zidx[i];
  atomicAdd(&t[z], m);
  atomicAdd(&cnt[z], 1);
  float s1 = block_sum256(slp, red);
  float s2 = block_sum256(m * m, red);
  if (threadIdx.x == 0) {
    atomicAdd(&scal[0], s1);   // sum_log_pdf
    atomicAdd(&scal[1], s2);   // m'm
  }
}

// ---------------------------------------------------------------------------
__global__ __launch_bounds__(256) void build_G(
    const float* __restrict__ dist, const float* __restrict__ s2e_p,
    const float* __restrict__ s2b_p, const float* __restrict__ ell_p,
    const int* __restrict__ cnt, float* __restrict__ G) {
  int idx = blockIdx.x * 256 + threadIdx.x;
  int j = idx >> 11;
  int k = idx & (Q - 1);
  float s2e = s2e_p[0], s2b = s2b_p[0], ell = ell_p[0];
  float sig2 = s2e + s2b;
  float a = (s2b / sig2) * expf(-dist[idx] / (2.0f * ell));
  float g = sqrtf((float)cnt[j] * (float)cnt[k]) * a;
  if (j == k) g += s2e / sig2;
  G[idx] = g;
}

// ---------------------------------------------------------------------------
__global__ __launch_bounds__(256) void matvec_kernel(
    const float* __restrict__ dist, const float* __restrict__ s2e_p,
    const float* __restrict__ s2b_p, const float* __restrict__ ell_p,
    const int* __restrict__ cnt, const float* __restrict__ t,
    float* __restrict__ z, float* __restrict__ scal) {
  __shared__ float red[4];
  int j = blockIdx.x;
  float s2e = s2e_p[0], s2b = s2b_p[0], ell = ell_p[0];
  float sig2 = s2e + s2b;
  float inv2ell = 1.0f / (2.0f * ell);
  float s = 0.0f;
  const float* drow = dist + (size_t)j * Q;
  for (int k = threadIdx.x; k < Q; k += 256) s += expf(-drow[k] * inv2ell) * t[k];
  float tot = block_sum256(s, red);
  if (threadIdx.x == 0) {
    float wj = (s2b / sig2) * tot;
    z[j] = sqrtf((float)cnt[j]) * wj;   // b = W^{1/2} w
    atomicAdd(&scal[2], t[j] * wj);     // t.w
  }
}

// ---------------------------------------------------------------------------
// Dataflow left-looking Cholesky (R8 structure, absmax-0-verified) with
// BUSY-BURN waits: every CU keeps issuing FMAs while waiting, so the clock
// governor never downclocks the chip (testing the DVFS-latency hypothesis).
__global__ __launch_bounds__(256) void chol_df(
    float* __restrict__ G, float* __restrict__ z, float* __restrict__ scal,
    int* __restrict__ rdy, const float* __restrict__ s2e_p,
    const float* __restrict__ s2b_p, float* __restrict__ out) {
  __shared__ __align__(16) float shA[64 * 68];
  __shared__ __align__(16) float shB[64 * 68];
  __shared__ __align__(16) float shT[64 * 68];
  __shared__ volatile int sh_go;
  int tid = threadIdx.x, lane = tid & 63, wv = tid >> 6;
  int tx = tid & 15, ty = tid >> 4;
  int bx = blockIdx.x;

  int dj = (bx < NT) ? bx : -1;
  int oi0 = -1, oj0 = -1, oi1 = -1, oj1 = -1, oi2 = -1, oj2 = -1;
  if (dj < 0) {
    int nod = 0, idx = 0;
    for (int j = 0; j < NT; ++j)
      for (int i = j + 2; i < NT; ++i) {   // pool: strictly below subdiagonal
        if ((idx % ODPOOL) + NT == bx) {
          if (nod == 0)      { oi0 = i; oj0 = j; }
          else if (nod == 1) { oi1 = i; oj1 = j; }
          else               { oi2 = i; oj2 = j; }
          ++nod;
        }
        ++idx;
      }
  }

  auto FLAG = [&](int i, int k) { return rdy + (i * NT + k) * FPAD; };
  int* DONE = rdy + NT * NT * FPAD;

  // Busy wait: wave 0 polls (all lanes, one coalesced load) with a short
  // burn between polls; waves 1-3 burn until the LDS go flag flips.
  auto waitflag = [&](const int* f) {
    if (tid == 0) sh_go = 0;
    __syncthreads();
    if (wv == 0) {
      while (__hip_atomic_load(f, __ATOMIC_RELAXED,
                               __HIP_MEMORY_SCOPE_AGENT) == 0)
        fma_burn(32);
      if (lane == 0) sh_go = 1;
    } else {
      while (sh_go == 0) fma_burn(64);
    }
    __syncthreads();
  };
  auto setflag = [&](int* f) {
    __hip_atomic_store(f, 1, __ATOMIC_RELAXED, __HIP_MEMORY_SCOPE_AGENT);
  };
  // cached transposed staging of a FINALIZED tile: sh[c*68+r] = T[r][c]
  auto stage_T = [&](const float* Gt, float* sh) {
    for (int it = 0; it < 4; ++it) {
      int idx = it * 256 + tid, r = idx >> 4, c4 = (idx & 15) * 4;
      float4 v = *(const float4*)(Gt + (size_t)r * Q + c4);
      sh[(c4 + 0) * 68 + r] = v.x; sh[(c4 + 1) * 68 + r] = v.y;
      sh[(c4 + 2) * 68 + r] = v.z; sh[(c4 + 3) * 68 + r] = v.w;
    }
  };
  auto mac16 = [&](const float* sA, const float* sB, float (&acc)[16]) {
    for (int p = 0; p < 64; ++p) {
      float4 a4 = *(const float4*)&sA[p * 68 + ty * 4];
      float4 b4 = *(const float4*)&sB[p * 68 + tx * 4];
      float av[4] = {a4.x, a4.y, a4.z, a4.w};
      float bv[4] = {b4.x, b4.y, b4.z, b4.w};
#pragma unroll
      for (int i4 = 0; i4 < 4; ++i4)
#pragma unroll
        for (int jj = 0; jj < 4; ++jj) acc[i4 * 4 + jj] -= av[i4] * bv[jj];
    }
  };
  auto init_acc = [&](float (&acc)[16], int ii, int jj) {  // COHERENT base read
    const float* B = G + (size_t)(ii * 64) * Q + jj * 64;
#pragma unroll
    for (int i4 = 0; i4 < 4; ++i4) {
      const float* rp = B + (size_t)(ty * 4 + i4) * Q + tx * 4;
      float2 u0 = coh_load8(rp), u1 = coh_load8(rp + 2);
      acc[i4 * 4 + 0] = u0.x; acc[i4 * 4 + 1] = u0.y;
      acc[i4 * 4 + 2] = u1.x; acc[i4 * 4 + 3] = u1.y;
    }
  };
  auto do_term = [&](float (&acc)[16], int ii, int jj, int k) {
    waitflag(FLAG(ii, k));
    waitflag(FLAG(jj, k));
    stage_T(G + (size_t)(ii * 64) * Q + k * 64, shA);
    stage_T(G + (size_t)(jj * 64) * Q + k * 64, shB);
    __syncthreads();
    mac16(shA, shB, acc);
    __syncthreads();
  };
  auto do_trsm = [&](float (&acc)[16], int ii, int jj, bool keepT) {
    waitflag(FLAG(jj, jj));
#pragma unroll
    for (int i4 = 0; i4 < 4; ++i4)
#pragma unroll
      for (int c4 = 0; c4 < 4; ++c4)
        shA[(ty * 4 + i4) * 68 + tx * 4 + c4] = acc[i4 * 4 + c4];
    const float* D = G + (size_t)(jj * 64) * Q + jj * 64;   // finalized diag
    for (int it = 0; it < 4; ++it) {
      int idx = it * 256 + tid, r = idx >> 4, c4 = (idx & 15) * 4;
      float4 v = *(const float4*)(D + (size_t)r * Q + c4);
      shB[r * 65 + c4 + 0] = v.x; shB[r * 65 + c4 + 1] = v.y;
      shB[r * 65 + c4 + 2] = v.z; shB[r * 65 + c4 + 3] = v.w;
    }
    __syncthreads();
    float dinv = 1.0f / shB[lane * 65 + lane];
    float* dst = G + (size_t)(ii * 64) * Q + jj * 64;
    for (int r16 = 0; r16 < 16; ++r16) {
      int r = wv * 16 + r16;
      float a = shA[r * 68 + lane];
      for (int p = 0; p < 64; ++p) {
        float xp = __shfl(a, p) * __shfl(dinv, p);
        if (lane > p) a -= xp * shB[lane * 65 + p];
      }
      float xr = a * dinv;
      coh_store4(dst + (size_t)r * Q + lane, xr);
      if (keepT) shT[lane * 68 + r] = xr;
    }
    asm volatile("s_waitcnt vmcnt(0)" ::: "memory");
    __syncthreads();
    if (tid == 0) setflag(FLAG(ii, jj));
    __syncthreads();
  };

  if (dj >= 0) {
    // =================== diag block: (dj,dj), (dj,dj-1), z chunk ==========
    float accD[16], accS[16];
    init_acc(accD, dj, dj);
    if (dj >= 1) init_acc(accS, dj, dj - 1);
    float zacc = 0.0f;
    if (wv == 0) zacc = coh_load4(z + dj * 64 + lane);

    for (int k = 0; k < dj - 1; ++k) {
      waitflag(FLAG(dj, k));
      waitflag(FLAG(dj - 1, k));
      stage_T(G + (size_t)(dj * 64) * Q + k * 64, shA);
      stage_T(G + (size_t)(dj - 1) * 64 * Q + k * 64, shB);
      __syncthreads();
      mac16(shA, shA, accD);
      mac16(shA, shB, accS);
      if (wv == 0) {   // z_dj -= L(dj,k) z_k
        float zk = coh_load4(z + k * 64 + lane);
        for (int p = 0; p < 64; ++p)
          zacc -= shA[p * 68 + lane] * __shfl(zk, p);
      }
      __syncthreads();
    }
    if (dj >= 1) {
      do_trsm(accS, dj, dj - 1, true);         // critical hop: waits diag(dj-1)
      mac16(shT, shT, accD);
      if (wv == 0) {
        float zk = coh_load4(z + (dj - 1) * 64 + lane);
        for (int p = 0; p < 64; ++p)
          zacc -= shT[p * 68 + lane] * __shfl(zk, p);
      }
      __syncthreads();
    }
    // factor accD
#pragma unroll
    for (int i4 = 0; i4 < 4; ++i4)
#pragma unroll
      for (int c4 = 0; c4 < 4; ++c4)
        shA[(ty * 4 + i4) * 68 + tx * 4 + c4] = accD[i4 * 4 + c4];
    __syncthreads();
    if (wv == 0) {
      float rr[64];
#pragma unroll
      for (int k4 = 0; k4 < 16; ++k4) {
        float4 v = *(const float4*)&shA[lane * 68 + k4 * 4];
        rr[k4 * 4 + 0] = v.x; rr[k4 * 4 + 1] = v.y;
        rr[k4 * 4 + 2] = v.z; rr[k4 * 4 + 3] = v.w;
      }
#pragma unroll
      for (int jj = 0; jj < 64; ++jj) {
        float vjj = __shfl(rr[jj], jj);
        float invd = rsqrtf(vjj);
        float lij = rr[jj] * invd;   // lane jj gets sqrt(vjj)
        rr[jj] = lij;
#pragma unroll
        for (int kk = 0; kk < 64; ++kk)
          if (kk > jj) rr[kk] -= lij * __shfl(lij, kk);
      }
      float dv = 1.0f;
#pragma unroll
      for (int kk = 0; kk < 64; ++kk)
        if (kk == lane) dv = rr[kk];
      float lg = logf(dv);
#pragma unroll
      for (int o = 32; o > 0; o >>= 1) lg += __shfl_down(lg, o);
      if (lane == 0) atomicAdd(&scal[3], lg);
      float* dst = G + (size_t)(dj * 64) * Q + dj * 64;
#pragma unroll
      for (int k2 = 0; k2 < 32; ++k2) {
        float a0 = (k2 * 2     <= lane) ? rr[k2 * 2]     : 0.0f;
        float a1 = (k2 * 2 + 1 <= lane) ? rr[k2 * 2 + 1] : 0.0f;
        coh_store8(dst + (size_t)lane * Q + k2 * 2, a0, a1);
      }
      // z forward-solve this chunk
      float dzi = 1.0f / dv;
      float a = zacc;
      for (int p = 0; p < 64; ++p) {
        float xp = __shfl(a, p) * __shfl(dzi, p);
        if (lane > p) a -= xp * rr[p];
      }
      a *= dzi;
      coh_store4(z + dj * 64 + lane, a);
      asm volatile("s_waitcnt vmcnt(0)" ::: "memory");
      if (lane == 0) setflag(FLAG(dj, dj));
      if (dj == NT - 1) {   // all deps transitively final
        float bv = 0.0f;
        for (int p = 0; p < NT; ++p) {
          float zi = coh_load4(z + p * 64 + lane);
          bv += zi * zi;
        }
#pragma unroll
        for (int o = 32; o > 0; o >>= 1) bv += __shfl_down(bv, o);
        if (lane == 0) {
          float s2e = s2e_p[0], s2b = s2b_p[0];
          float sig2 = s2e + s2b;
          float c = s2e / sig2;
          float slp = coh_load4(&scal[0]), mtm = coh_load4(&scal[1]);
          float tw = coh_load4(&scal[2]), sl = coh_load4(&scal[3]);
          float tty = (tw - bv) / c;
          float mrm = (mtm - tty) / c;
          float logdetR = (float)(NOBS - Q) * logf(c) + 2.0f * sl;
          coh_store4(out,
              0.5f * logdetR + 0.5f * mrm - 0.5f * mtm + 0.5f * slp);
          asm volatile("s_waitcnt vmcnt(0)" ::: "memory");
          setflag(DONE);
        }
      }
    }
    __syncthreads();
    if (dj != NT - 1) waitflag(DONE);   // burn until the end: keep clocks up
  } else {
    // =================== off-diag pool block: up to 3 tiles, i>=j+2 =======
    float accO0[16], accO1[16], accO2[16];
    if (oj0 >= 0) init_acc(accO0, oi0, oj0);
    if (oj1 >= 0) init_acc(accO1, oi1, oj1);
    if (oj2 >= 0) init_acc(accO2, oi2, oj2);
    for (int k = 0; k < NT; ++k) {
      if (oj0 == k) do_trsm(accO0, oi0, k, false);
      if (oj1 == k) do_trsm(accO1, oi1, k, false);
      if (oj2 == k) do_trsm(accO2, oi2, k, false);
      if (oj0 > k) do_term(accO0, oi0, oj0, k);
      if (oj1 > k) do_term(accO1, oi1, oj1, k);
      if (oj2 > k) do_term(accO2, oi2, oj2, k);
    }
    waitflag(DONE);   // burn until the end: keep clocks up
  }
}

// ---------------------------------------------------------------------------
extern "C" void kernel_launch(void* const* d_in, const int* in_sizes, int n_in,
                              void* d_out, int out_size, void* d_ws, size_t ws_size,
                              hipStream_t stream) {
  const float* yt   = (const float*)d_in[0];
  const float* yp   = (const float*)d_in[1];
  const int*   zidx = (const int*)d_in[2];
  const float* dist = (const float*)d_in[3];
  const float* s2e  = (const float*)d_in[4];
  const float* s2b  = (const float*)d_in[5];
  const float* ell  = (const float*)d_in[6];

  float* ws   = (float*)d_ws;
  float* G    = ws;                         // Q*Q floats = 16 MB
  float* z    = ws + (size_t)Q * Q;         // Q
  float* t    = z + Q;                      // Q
  int*   cnt  = (int*)(t + Q);              // Q ints
  float* scal = t + 2 * Q;                  // 8: slp, mtm, tw, sumlogL
  int*   rdy  = (int*)(scal + 8);           // NT*NT+1 flags, 64B-padded

  // zero t, cnt, scal, rdy+DONE — re-zeroed EVERY launch
  hipMemsetAsync(t, 0, (2 * Q + 8 + (NT * NT + 1) * FPAD) * sizeof(float),
                 stream);

  obs_kernel<<<NOBS / 256, 256, 0, stream>>>(yt, yp, zidx, s2e, s2b, t, cnt, scal);
  build_G<<<(Q * Q) / 256, 256, 0, stream>>>(dist, s2e, s2b, ell, cnt, G);
  matvec_kernel<<<Q, 256, 0, stream>>>(dist, s2e, s2b, ell, cnt, t, z, scal);

  chol_df<<<dim3(NBLK), dim3(256), 0, stream>>>(
      G, z, scal, rdy, s2e, s2b, (float*)d_out);
}